// Round 9
// baseline (1764.577 us; speedup 1.0000x reference)
//
#include <hip/hip_runtime.h>

constexpr int B_ = 128, S_ = 25, NF_ = 196, ENC_ = 512, ATT_ = 512;
constexpr int H_ = 512, E_ = 256, V_ = 10000, G4_ = 2048;
constexpr int VPAD_ = 10112;  // 79*128

typedef __attribute__((ext_vector_type(8))) __bf16 bf16x8;
typedef __attribute__((ext_vector_type(4))) __bf16 bf16x4;
typedef __attribute__((ext_vector_type(4))) float f32x4;

__device__ __forceinline__ float bflo(unsigned u) {
    return __builtin_bit_cast(float, u << 16);
}
__device__ __forceinline__ float bfhi(unsigned u) {
    return __builtin_bit_cast(float, u & 0xffff0000u);
}
__device__ __forceinline__ float fast_tanhf(float x) {
    x = fminf(fmaxf(x, -15.f), 15.f);
    return 1.f - 2.f * __fdividef(1.f, __expf(2.f * x) + 1.f);
}
__device__ __forceinline__ float fast_sigf(float x) {
    x = fminf(fmaxf(x, -30.f), 30.f);
    return __fdividef(1.f, 1.f + __expf(-x));
}

// gate-interleaved permutation: col n -> weight row pi(n)
__device__ __forceinline__ int gperm(int n) {
    int j = (n & 15) + ((n >> 6) << 4);
    int g = (n >> 4) & 3;
    return g * 512 + j;
}

// ---------------- setup kernels ----------------
__global__ __launch_bounds__(256) void k_cvt(const float* __restrict__ s,
                                             __bf16* __restrict__ d, int n4) {
    int i = blockIdx.x * 256 + threadIdx.x;
    if (i >= n4) return;
    float4 v = *(const float4*)&s[(size_t)i * 4];
    bf16x4 o;
    o[0] = (__bf16)v.x; o[1] = (__bf16)v.y; o[2] = (__bf16)v.z; o[3] = (__bf16)v.w;
    *(bf16x4*)&d[(size_t)i * 4] = o;
}

__global__ __launch_bounds__(256) void k_cvt_fcw(const float* __restrict__ s,
                                                 __bf16* __restrict__ d) {
    int i = blockIdx.x * 256 + threadIdx.x;
    if (i >= VPAD_ * 512 / 4) return;
    int e = i * 4;
    int row = e >> 9;
    bf16x4 o;
    if (row < V_) {
        float4 v = *(const float4*)&s[(size_t)row * 512 + (e & 511)];
        o[0] = (__bf16)v.x; o[1] = (__bf16)v.y; o[2] = (__bf16)v.z; o[3] = (__bf16)v.w;
    } else {
        o[0] = o[1] = o[2] = o[3] = (__bf16)0.f;
    }
    *(bf16x4*)&d[(size_t)e] = o;
}

// Ww[j][k] f32 -> W2[k][jp] u32 = pack(bf16 Ww[2jp][k], bf16 Ww[2jp+1][k])
__global__ __launch_bounds__(256) void k_pack_ww(const float* __restrict__ Ww,
                                                 unsigned* __restrict__ W2) {
    __shared__ float Ts[32][65];
    int t = threadIdx.x;
    int k0 = blockIdx.x * 32, j0 = blockIdx.y * 64;
    int c = t & 31, rr = t >> 5;
#pragma unroll
    for (int i = 0; i < 8; ++i) {
        int j = j0 + rr + i * 8;
        Ts[c][rr + i * 8] = Ww[(size_t)j * 512 + k0 + c];
    }
    __syncthreads();
#pragma unroll
    for (int i = 0; i < 4; ++i) {
        int kr = (t >> 5) + i * 8;
        int jc = t & 31;
        __bf16 b0 = (__bf16)Ts[kr][2 * jc], b1 = (__bf16)Ts[kr][2 * jc + 1];
        unsigned u = (unsigned)__builtin_bit_cast(unsigned short, b0)
                   | ((unsigned)__builtin_bit_cast(unsigned short, b1) << 16);
        W2[(size_t)(k0 + kr) * 256 + (j0 >> 1) + jc] = u;
    }
}

// W_ih[:, :256] permuted rows -> bf16 [2048][256] (gate-interleaved)
__global__ __launch_bounds__(256) void k_cvt_wih_r(const float* __restrict__ W_ih,
                                                   __bf16* __restrict__ o) {
    int n = blockIdx.x, k = threadIdx.x;
    int row = gperm(n);
    o[(size_t)n * 256 + k] = (__bf16)W_ih[(size_t)row * 768 + k];
}

// Wcat[n][k]: k<512 -> W_ih[pi(n)][256+k], else W_hh[pi(n)][k-512]   (bf16)
__global__ __launch_bounds__(256) void k_pack_wcat(const float* __restrict__ W_ih,
                                                   const float* __restrict__ W_hh,
                                                   __bf16* __restrict__ Wcat) {
    int n = blockIdx.x, t = threadIdx.x;
    int row = gperm(n);
#pragma unroll
    for (int i = 0; i < 4; ++i) {
        int k = t + i * 256;
        float v = (k < 512) ? W_ih[(size_t)row * 768 + 256 + k]
                            : W_hh[(size_t)row * 512 + (k - 512)];
        Wcat[(size_t)n * 1024 + k] = (__bf16)v;
    }
}

__global__ __launch_bounds__(256) void k_pack_biasr(const float* __restrict__ b_ih,
                                                    const float* __restrict__ b_hh,
                                                    float* __restrict__ bsum_r) {
    int n = blockIdx.x * 256 + threadIdx.x;
    int row = gperm(n);
    bsum_r[n] = b_ih[row] + b_hh[row];
}

__global__ __launch_bounds__(256) void k_embed(const int* __restrict__ dec,
                                               const float* __restrict__ emb,
                                               const float* __restrict__ pose,
                                               __bf16* __restrict__ out) {
    int bx = blockIdx.x;
    int s = bx >> 7, b = bx & 127;
    int e = threadIdx.x;
    int tok = dec[b * S_ + s];
    out[(size_t)bx * E_ + e] = (__bf16)(emb[tok * E_ + e] + pose[s * E_ + e]);
}

// mean_enc -> h0 (bf16 into Abuf0 h-part), c0 (f32 cbuf). Coalesced GEMV (wave-per-j).
__global__ __launch_bounds__(1024) void k_init2(const float* __restrict__ enc,
                                                const float* __restrict__ ihw, const float* __restrict__ ihb,
                                                const float* __restrict__ icw, const float* __restrict__ icb,
                                                __bf16* __restrict__ Abuf0, float* __restrict__ cbuf) {
    __shared__ float pm[1024];
    __shared__ __align__(16) float mean[512];
    int b = blockIdx.x, t = threadIdx.x;
    int d = t & 511, q = t >> 9;
    const float* ep = enc + ((size_t)b * 196 + q * 98) * 512 + d;
    float sum = 0.f;
#pragma unroll 7
    for (int n = 0; n < 98; ++n) sum += ep[(size_t)n * 512];
    pm[t] = sum;
    __syncthreads();
    if (t < 512) mean[t] = (pm[t] + pm[t + 512]) * (1.f / 196.f);
    __syncthreads();
    int w = t >> 6, ln = t & 63;
    float4 m4a = *(const float4*)&mean[ln * 8];
    float4 m4b = *(const float4*)&mean[ln * 8 + 4];
#pragma unroll 4
    for (int i = 0; i < 32; ++i) {
        int j = i * 16 + w;
        const float4* wh = (const float4*)&ihw[(size_t)j * 512 + ln * 8];
        const float4* wc = (const float4*)&icw[(size_t)j * 512 + ln * 8];
        float4 ha = wh[0], hb = wh[1], ca = wc[0], cb = wc[1];
        float ah = m4a.x * ha.x + m4a.y * ha.y + m4a.z * ha.z + m4a.w * ha.w
                 + m4b.x * hb.x + m4b.y * hb.y + m4b.z * hb.z + m4b.w * hb.w;
        float ac = m4a.x * ca.x + m4a.y * ca.y + m4a.z * ca.z + m4a.w * ca.w
                 + m4b.x * cb.x + m4b.y * cb.y + m4b.z * cb.z + m4b.w * cb.w;
#pragma unroll
        for (int off = 32; off; off >>= 1) {
            ah += __shfl_xor(ah, off);
            ac += __shfl_xor(ac, off);
        }
        if (ln == 0) {
            Abuf0[(size_t)b * 1024 + 512 + j] = (__bf16)(ah + ihb[j]);
            cbuf[b * 512 + j] = ac + icb[j];
        }
    }
}

// ---------------- bf16 MFMA GEMM (proven core, + lda param) ----------------
template<int MODE>
__global__ __launch_bounds__(256) void k_mfma_gemm(
    const __bf16* __restrict__ A, int lda, const __bf16* __restrict__ Bm,
    const float* __restrict__ bias1, void* __restrict__ Cout,
    int K, int Nreal, int ldc) {
    __shared__ __align__(16) __bf16 As[128 * 64];
    __shared__ __align__(16) __bf16 Bs[128 * 64];
    int tid = threadIdx.x;
    int lane = tid & 63, w = tid >> 6;
    int m0 = blockIdx.x * 128, n0 = blockIdx.y * 128;
    int wm = (w & 1) * 64, wn = (w >> 1) * 64;
    f32x4 acc[4][4] = {};
    int srow = tid >> 3;
    int ke = (tid & 7) * 8;
    int kgw = tid & 7;

    for (int k0 = 0; k0 < K; k0 += 64) {
#pragma unroll
        for (int it = 0; it < 4; ++it) {
            int row = it * 32 + srow;
            bf16x8 av = *(const bf16x8*)(A + (size_t)(m0 + row) * lda + k0 + ke);
            bf16x8 bv = *(const bf16x8*)(Bm + (size_t)(n0 + row) * K + k0 + ke);
            int kg = kgw ^ (row & 7);
            *(bf16x8*)&As[row * 64 + kg * 8] = av;
            *(bf16x8*)&Bs[row * 64 + kg * 8] = bv;
        }
        __syncthreads();
        bf16x8 af[4][2], bfr[4][2];
#pragma unroll
        for (int f = 0; f < 4; ++f) {
#pragma unroll
            for (int ks = 0; ks < 2; ++ks) {
                int ra = wm + f * 16 + (lane & 15);
                int rb = wn + f * 16 + (lane & 15);
                int kgl = ks * 4 + (lane >> 4);
                af[f][ks]  = *(const bf16x8*)&As[ra * 64 + (kgl ^ (ra & 7)) * 8];
                bfr[f][ks] = *(const bf16x8*)&Bs[rb * 64 + (kgl ^ (rb & 7)) * 8];
            }
        }
#pragma unroll
        for (int fm = 0; fm < 4; ++fm)
#pragma unroll
            for (int fn = 0; fn < 4; ++fn)
#pragma unroll
                for (int ks = 0; ks < 2; ++ks)
                    acc[fm][fn] = __builtin_amdgcn_mfma_f32_16x16x32_bf16(
                        af[fm][ks], bfr[fn][ks], acc[fm][fn], 0, 0, 0);
        __syncthreads();
    }
    int cm = (lane >> 4) * 4, cn = lane & 15;
#pragma unroll
    for (int fm = 0; fm < 4; ++fm) {
#pragma unroll
        for (int fn = 0; fn < 4; ++fn) {
#pragma unroll
            for (int r = 0; r < 4; ++r) {
                int gm = m0 + wm + fm * 16 + cm + r;
                int gn = n0 + wn + fn * 16 + cn;
                float v = acc[fm][fn][r];
                if (MODE == 0) {
                    if (gn < Nreal) {
                        int orow = (gm & 127) * S_ + (gm >> 7);
                        ((float*)Cout)[(size_t)orow * ldc + gn] = v + bias1[gn];
                    }
                } else {
                    ((__bf16*)Cout)[(size_t)gm * ldc + gn] = (__bf16)(v + bias1[gn]);
                }
            }
        }
    }
}

// ---------------- K1: attention, grid (128,2): block = (b, 98-row half) ----------------
// Max-free partial softmax: E=exp(s), partial l and unnormalized ctx; combine in k_gates2.
__global__ __launch_bounds__(512) void k_attn3(
    const __bf16* __restrict__ u_hs,      // [25088][512] bf16
    const unsigned* __restrict__ enc2,    // enc bf16 pairs [25088][256]
    const unsigned* __restrict__ W2,      // [512][256] packed Ww^T
    const float* __restrict__ Wb, const float* __restrict__ Aw,
    const __bf16* __restrict__ Abuf,      // read h from cols 512..1023
    float* __restrict__ pctx,             // [2][128][512] unnormalized partial ctx
    float* __restrict__ lpart,            // [2][128] partial sums
    float* __restrict__ esg) {            // [128][256] E values
    __shared__ __align__(16) float hs[512];
    __shared__ float wah[512];
    __shared__ float pc[1024];
    __shared__ float es[100];
    int b = blockIdx.x, hh = blockIdx.y, t = threadIdx.x;
    int ln = t & 63, w = t >> 6;

    // h (bf16) -> LDS f32
    if (t < 256) {
        unsigned u = ((const unsigned*)Abuf)[b * 512 + 256 + t];
        hs[2 * t] = bflo(u); hs[2 * t + 1] = bfhi(u);
    }
    __syncthreads();
    // w_ah = h @ Ww^T + Wb  (coalesced packed W2, 2-way k-split — R6-proven)
    {
        int jp = t & 255, q = t >> 8;
        float a0 = 0.f, a1 = 0.f;
        const unsigned* wp = W2 + (size_t)(q * 256) * 256 + jp;
        const float4* h4 = (const float4*)(hs + q * 256);
#pragma unroll 4
        for (int k4 = 0; k4 < 64; ++k4) {
            float4 hk = h4[k4];
            unsigned w0 = wp[(k4 * 4 + 0) * 256];
            unsigned w1 = wp[(k4 * 4 + 1) * 256];
            unsigned w2 = wp[(k4 * 4 + 2) * 256];
            unsigned w3 = wp[(k4 * 4 + 3) * 256];
            a0 += hk.x * bflo(w0); a1 += hk.x * bfhi(w0);
            a0 += hk.y * bflo(w1); a1 += hk.y * bfhi(w1);
            a0 += hk.z * bflo(w2); a1 += hk.z * bfhi(w2);
            a0 += hk.w * bflo(w3); a1 += hk.w * bfhi(w3);
        }
        pc[q * 512 + 2 * jp] = a0;
        pc[q * 512 + 2 * jp + 1] = a1;
    }
    __syncthreads();
    wah[t] = pc[t] + pc[512 + t] + Wb[t];
    __syncthreads();
    // scores -> E = exp(s) for this half's 98 rows (no max: |s| small; Ab cancels)
    {
        float av[8], wv[8];
#pragma unroll
        for (int i = 0; i < 8; ++i) { av[i] = Aw[ln * 8 + i]; wv[i] = wah[ln * 8 + i]; }
        for (int nl = w; nl < 98; nl += 8) {
            int n = hh * 98 + nl;
            bf16x8 u8 = *(const bf16x8*)(u_hs + ((size_t)(b * NF_ + n)) * 512 + ln * 8);
            float acc = 0.f;
#pragma unroll
            for (int i = 0; i < 8; ++i)
                acc += fast_tanhf((float)u8[i] + wv[i]) * av[i];
#pragma unroll
            for (int off = 32; off; off >>= 1) acc += __shfl_xor(acc, off);
            if (ln == 0) es[nl] = __expf(acc);
        }
    }
    __syncthreads();
    // unnormalized ctx partial: 2-way row split over 98 rows
    {
        int p2 = t & 255, q2 = t >> 8;
        float c0 = 0.f, c1 = 0.f;
        for (int i = q2; i < 98; i += 2) {
            unsigned u = enc2[((size_t)(b * NF_ + hh * 98 + i)) * 256 + p2];
            float a = es[i];
            c0 += a * bflo(u); c1 += a * bfhi(u);
        }
        pc[q2 * 512 + 2 * p2] = c0;
        pc[q2 * 512 + 2 * p2 + 1] = c1;
    }
    __syncthreads();
    pctx[((size_t)(hh * 128 + b)) * 512 + t] = pc[t] + pc[512 + t];
    if (t < 98) esg[b * 256 + hh * 98 + t] = es[t];
    if (t < 64) {   // l = sum of 98 E values (single-wave reduce)
        float v = es[t] + ((t + 64 < 98) ? es[t + 64] : 0.f);
#pragma unroll
        for (int off = 32; off; off >>= 1) v += __shfl_xor(v, off);
        if (t == 0) lpart[hh * 128 + b] = v;
    }
}

// ---------------- K2: gates MFMA GEMM with fused ctx-combine + alphas + LSTM ----------------
// grid (4,32), 256 thr. Pre-phase: inv = 1/(l0+l1); ctxL (LDS bf16, swizzled) = (p0+p1)*inv.
// Main loop: kh=0 waves read A from ctxL (no staging); kh=1 from As (h-half staging).
__global__ __launch_bounds__(256) void k_gates2(
    const __bf16* __restrict__ Abuf,      // [128][1024]: h(s) in cols 512..1023
    const __bf16* __restrict__ Wcat,      // [2048][1024]
    const __bf16* __restrict__ gatespre,  // [3200][2048] bf16, gate-interleaved cols
    float* __restrict__ cbuf,             // [128][512] f32
    __bf16* __restrict__ AbufN,           // write h(s+1) into cols 512..1023
    __bf16* __restrict__ Hall_bf,         // [26][128][512]
    const float* __restrict__ pctx, const float* __restrict__ lpart,
    const float* __restrict__ esg, float* __restrict__ alphas, int s) {
    __shared__ __align__(16) __bf16 ctxL[32 * 512];   // 32 KB
    __shared__ __align__(16) __bf16 As[32 * 64];      // 4 KB (h-half staging)
    __shared__ __align__(16) __bf16 Bs[2][64 * 64];   // 16 KB
    __shared__ float Red[2048];                        // 8 KB
    __shared__ float invs[32];
    int tid = threadIdx.x;
    int lane = tid & 63, w = tid >> 6;
    int m0 = blockIdx.x * 32, n0 = blockIdx.y * 64;
    int kh = w >> 1, wm = (w & 1) * 16;
    int srow = tid >> 3;          // 0..31
    int ke = (tid & 7) * 8;
    int kgw = tid & 7;

    // pre-phase: inv per row
    if (tid < 32) invs[tid] = __fdividef(1.f, lpart[m0 + tid] + lpart[128 + m0 + tid]);
    __syncthreads();
    // ctx combine -> ctxL (swizzled bf16), coalesced float2 pairs
    for (int q = tid; q < 8192; q += 256) {
        int row = q >> 8;
        int kk = (q & 255) * 2;
        float2 v0 = *(const float2*)&pctx[((size_t)(m0 + row)) * 512 + kk];
        float2 v1 = *(const float2*)&pctx[((size_t)(128 + m0 + row)) * 512 + kk];
        float iv = invs[row];
        int base = row * 512 + (kk & ~63) + ((((kk >> 3) & 7) ^ (row & 7)) << 3) + (kk & 7);
        ctxL[base] = (__bf16)((v0.x + v1.x) * iv);
        ctxL[base + 1] = (__bf16)((v0.y + v1.y) * iv);
    }
    // alphas (only the n0==0 column-blocks)
    if (blockIdx.y == 0) {
        for (int q = tid; q < 32 * 256; q += 256) {
            int row = q >> 8, n = q & 255;
            if (n < NF_)
                alphas[((size_t)(m0 + row) * S_ + s) * NF_ + n] =
                    esg[(m0 + row) * 256 + n] * invs[row];
        }
    }
    __syncthreads();

    f32x4 acc[4] = {};
    for (int k0 = 0; k0 < 512; k0 += 64) {
        // stage A h-half + both B halves
        {
            bf16x8 av = *(const bf16x8*)(Abuf + (size_t)(m0 + srow) * 1024 + 512 + k0 + ke);
            *(bf16x8*)&As[srow * 64 + (kgw ^ (srow & 7)) * 8] = av;
#pragma unroll
            for (int h = 0; h < 2; ++h) {
                int kb = h * 512 + k0;
#pragma unroll
                for (int it = 0; it < 2; ++it) {
                    int row = it * 32 + srow;
                    bf16x8 bv = *(const bf16x8*)(Wcat + (size_t)(n0 + row) * 1024 + kb + ke);
                    *(bf16x8*)&Bs[h][row * 64 + (kgw ^ (row & 7)) * 8] = bv;
                }
            }
        }
        __syncthreads();
        bf16x8 af[2], bfr[4][2];
#pragma unroll
        for (int ks = 0; ks < 2; ++ks) {
            int ra = wm + (lane & 15);
            int kgl = ks * 4 + (lane >> 4);
            if (kh == 0)
                af[ks] = *(const bf16x8*)&ctxL[ra * 512 + k0 + ((kgl ^ (ra & 7))) * 8];
            else
                af[ks] = *(const bf16x8*)&As[ra * 64 + ((kgl ^ (ra & 7))) * 8];
#pragma unroll
            for (int fn = 0; fn < 4; ++fn) {
                int rb = fn * 16 + (lane & 15);
                bfr[fn][ks] = *(const bf16x8*)&Bs[kh][rb * 64 + ((kgl ^ (rb & 7))) * 8];
            }
        }
#pragma unroll
        for (int fn = 0; fn < 4; ++fn)
#pragma unroll
            for (int ks = 0; ks < 2; ++ks)
                acc[fn] = __builtin_amdgcn_mfma_f32_16x16x32_bf16(
                    af[ks], bfr[fn][ks], acc[fn], 0, 0, 0);
        __syncthreads();
    }
    // reduce the kh=1 half into kh=0 waves
    int base = ((w & 1) * 64 + lane) * 16;
    if (kh == 1) {
#pragma unroll
        for (int fn = 0; fn < 4; ++fn)
#pragma unroll
            for (int r = 0; r < 4; ++r) Red[base + fn * 4 + r] = acc[fn][r];
    }
    __syncthreads();
    if (kh == 0) {
#pragma unroll
        for (int fn = 0; fn < 4; ++fn)
#pragma unroll
            for (int r = 0; r < 4; ++r) acc[fn][r] += Red[base + fn * 4 + r];
        // epilogue: lane owns unit j for all 4 gates (fn = gate)
        int cm = (lane >> 4) * 4, cn = lane & 15;
        int j = (n0 >> 6) * 16 + cn;
#pragma unroll
        for (int r = 0; r < 4; ++r) {
            int b = m0 + wm + cm + r;
            const __bf16* gp = gatespre + ((size_t)(s * B_ + b)) * G4_ + n0 + cn;
            float qi = acc[0][r] + (float)gp[0];
            float qf = acc[1][r] + (float)gp[16];
            float qg = acc[2][r] + (float)gp[32];
            float qo = acc[3][r] + (float)gp[48];
            float ig = fast_sigf(qi), fg = fast_sigf(qf);
            float gg = fast_tanhf(qg), og = fast_sigf(qo);
            int ci = b * 512 + j;
            float cnew = fg * cbuf[ci] + ig * gg;
            float hn = og * fast_tanhf(cnew);
            cbuf[ci] = cnew;
            __bf16 hb = (__bf16)hn;
            AbufN[(size_t)b * 1024 + 512 + j] = hb;
            Hall_bf[(size_t)(s + 1) * 65536 + ci] = hb;
        }
    }
}

extern "C" void kernel_launch(void* const* d_in, const int* in_sizes, int n_in,
                              void* d_out, int out_size, void* d_ws, size_t ws_size,
                              hipStream_t stream) {
    const int*   dec  = (const int*)d_in[0];
    const float* enc  = (const float*)d_in[1];
    const float* emb  = (const float*)d_in[2];
    const float* pose = (const float*)d_in[3];
    const float* Uw   = (const float*)d_in[4];
    const float* Ub   = (const float*)d_in[5];
    const float* Ww   = (const float*)d_in[6];
    const float* Wb   = (const float*)d_in[7];
    const float* Aw   = (const float*)d_in[8];
    // d_in[9] = Ab: cancels in softmax
    const float* ihw  = (const float*)d_in[10];
    const float* ihb  = (const float*)d_in[11];
    const float* icw  = (const float*)d_in[12];
    const float* icb  = (const float*)d_in[13];
    const float* W_ih = (const float*)d_in[14];
    const float* W_hh = (const float*)d_in[15];
    const float* b_ih = (const float*)d_in[16];
    const float* b_hh = (const float*)d_in[17];
    const float* fcw  = (const float*)d_in[18];
    const float* fcb  = (const float*)d_in[19];
    float* out = (float*)d_out;
    char*  wsb = (char*)d_ws;

    // ---- workspace layout (bytes), ~88 MB ----
    size_t o = 0;
    __bf16*   enc_bf   = (__bf16*)(wsb + o); o += (size_t)25088 * 512 * 2;   // 25,690,112
    __bf16*   u_hs_bf  = (__bf16*)(wsb + o); o += (size_t)25088 * 512 * 2;   // 25,690,112
    __bf16*   gpre_bf  = (__bf16*)(wsb + o); o += (size_t)3200 * 2048 * 2;   // 13,107,200
    __bf16*   Hall_bf  = (__bf16*)(wsb + o); o += (size_t)26 * 65536 * 2;    //  3,407,872
    float*    cbuf     = (float*)(wsb + o);  o += (size_t)65536 * 4;         //    262,144
    __bf16*   Abuf     = (__bf16*)(wsb + o); o += (size_t)2 * 128 * 1024 * 2;//    524,288
    __bf16*   Uw_bf    = (__bf16*)(wsb + o); o += (size_t)262144 * 2;        //    524,288
    unsigned* W2       = (unsigned*)(wsb + o); o += (size_t)512 * 256 * 4;   //    524,288
    __bf16*   WihE_r   = (__bf16*)(wsb + o); o += (size_t)2048 * 256 * 2;    //  1,048,576
    __bf16*   embeds_bf= (__bf16*)(wsb + o); o += (size_t)3200 * 256 * 2;    //  1,638,400
    __bf16*   Wcat     = (__bf16*)(wsb + o); o += (size_t)2048 * 1024 * 2;   //  4,194,304
    float*    bsum_r   = (float*)(wsb + o);  o += (size_t)2048 * 4;          //      8,192
    __bf16*   fcw_bf   = (__bf16*)(wsb + o); o += (size_t)VPAD_ * 512 * 2;   // 10,354,688
    float*    pctx     = (float*)(wsb + o);  o += (size_t)2 * 128 * 512 * 4; //    524,288
    float*    lpart    = (float*)(wsb + o);  o += (size_t)256 * 4;           //      1,024
    float*    esg      = (float*)(wsb + o);  o += (size_t)128 * 256 * 4;     //    131,072

    // ---- setup (independent) ----
    k_cvt<<<12544, 256, 0, stream>>>(enc, enc_bf, 3211264);
    k_cvt<<<256, 256, 0, stream>>>(Uw, Uw_bf, 65536);
    k_pack_ww<<<dim3(16, 8), 256, 0, stream>>>(Ww, W2);
    k_cvt_wih_r<<<2048, 256, 0, stream>>>(W_ih, WihE_r);
    k_pack_wcat<<<2048, 256, 0, stream>>>(W_ih, W_hh, Wcat);
    k_pack_biasr<<<8, 256, 0, stream>>>(b_ih, b_hh, bsum_r);
    k_embed<<<S_ * B_, 256, 0, stream>>>(dec, emb, pose, embeds_bf);
    k_init2<<<B_, 1024, 0, stream>>>(enc, ihw, ihb, icw, icb, Abuf, cbuf);
    k_cvt_fcw<<<5056, 256, 0, stream>>>(fcw, fcw_bf);

    // u_hs = enc @ Uw^T + Ub -> bf16 [25088,512]
    k_mfma_gemm<1><<<dim3(196, 4), 256, 0, stream>>>(enc_bf, 512, Uw_bf, Ub,
                                                     u_hs_bf, 512, 512, 512);
    // gates_pre = embeds @ WihE_r^T + bsum_r -> bf16 [3200,2048] (gate-interleaved cols)
    k_mfma_gemm<1><<<dim3(25, 16), 256, 0, stream>>>(embeds_bf, 256, WihE_r, bsum_r,
                                                     gpre_bf, 256, 2048, 2048);

    // ---- 25 steps x 2 kernels ----
    for (int s = 0; s < S_; ++s) {
        __bf16* Ap = Abuf + (size_t)(s & 1) * 131072;
        __bf16* An = Abuf + (size_t)((s + 1) & 1) * 131072;
        k_attn3<<<dim3(B_, 2), 512, 0, stream>>>(u_hs_bf, (const unsigned*)enc_bf, W2,
                                                 Wb, Aw, Ap, pctx, lpart, esg);
        k_gates2<<<dim3(4, 32), 256, 0, stream>>>(Ap, Wcat, gpre_bf, cbuf, An, Hall_bf,
                                                  pctx, lpart, esg, out + 32000000, s);
    }

    // outs = Hall_bf[1..25] @ fcn_w^T + fcn_b -> f32 [B,S,V]
    k_mfma_gemm<0><<<dim3(25, 79), 256, 0, stream>>>(Hall_bf + 65536, 512, fcw_bf, fcb,
                                                     out, 512, V_, V_);
}

// Round 11
// 1410.213 us; speedup vs baseline: 1.2513x; 1.2513x over previous
//
#include <hip/hip_runtime.h>

constexpr int B_ = 128, S_ = 25, NF_ = 196, ENC_ = 512, ATT_ = 512;
constexpr int H_ = 512, E_ = 256, V_ = 10000, G4_ = 2048;
constexpr int VPAD_ = 10112;  // 79*128

typedef __attribute__((ext_vector_type(8))) __bf16 bf16x8;
typedef __attribute__((ext_vector_type(4))) __bf16 bf16x4;
typedef __attribute__((ext_vector_type(4))) float f32x4;

__device__ __forceinline__ float bflo(unsigned u) {
    return __builtin_bit_cast(float, u << 16);
}
__device__ __forceinline__ float bfhi(unsigned u) {
    return __builtin_bit_cast(float, u & 0xffff0000u);
}
__device__ __forceinline__ float fast_tanhf(float x) {
    x = fminf(fmaxf(x, -15.f), 15.f);
    return 1.f - 2.f * __fdividef(1.f, __expf(2.f * x) + 1.f);
}
__device__ __forceinline__ float fast_sigf(float x) {
    x = fminf(fmaxf(x, -30.f), 30.f);
    return __fdividef(1.f, 1.f + __expf(-x));
}

// gate-interleaved permutation: col n -> weight row pi(n)
__device__ __forceinline__ int gperm(int n) {
    int j = (n & 15) + ((n >> 6) << 4);
    int g = (n >> 4) & 3;
    return g * 512 + j;
}

// ---------------- setup kernels ----------------
__global__ __launch_bounds__(256) void k_cvt(const float* __restrict__ s,
                                             __bf16* __restrict__ d, int n4) {
    int i = blockIdx.x * 256 + threadIdx.x;
    if (i >= n4) return;
    float4 v = *(const float4*)&s[(size_t)i * 4];
    bf16x4 o;
    o[0] = (__bf16)v.x; o[1] = (__bf16)v.y; o[2] = (__bf16)v.z; o[3] = (__bf16)v.w;
    *(bf16x4*)&d[(size_t)i * 4] = o;
}

__global__ __launch_bounds__(256) void k_cvt_fcw(const float* __restrict__ s,
                                                 __bf16* __restrict__ d) {
    int i = blockIdx.x * 256 + threadIdx.x;
    if (i >= VPAD_ * 512 / 4) return;
    int e = i * 4;
    int row = e >> 9;
    bf16x4 o;
    if (row < V_) {
        float4 v = *(const float4*)&s[(size_t)row * 512 + (e & 511)];
        o[0] = (__bf16)v.x; o[1] = (__bf16)v.y; o[2] = (__bf16)v.z; o[3] = (__bf16)v.w;
    } else {
        o[0] = o[1] = o[2] = o[3] = (__bf16)0.f;
    }
    *(bf16x4*)&d[(size_t)e] = o;
}

// Ww[j][k] f32 -> W2[k][jp] u32 = pack(bf16 Ww[2jp][k], bf16 Ww[2jp+1][k])
__global__ __launch_bounds__(256) void k_pack_ww(const float* __restrict__ Ww,
                                                 unsigned* __restrict__ W2) {
    __shared__ float Ts[32][65];
    int t = threadIdx.x;
    int k0 = blockIdx.x * 32, j0 = blockIdx.y * 64;
    int c = t & 31, rr = t >> 5;
#pragma unroll
    for (int i = 0; i < 8; ++i) {
        int j = j0 + rr + i * 8;
        Ts[c][rr + i * 8] = Ww[(size_t)j * 512 + k0 + c];
    }
    __syncthreads();
#pragma unroll
    for (int i = 0; i < 4; ++i) {
        int kr = (t >> 5) + i * 8;
        int jc = t & 31;
        __bf16 b0 = (__bf16)Ts[kr][2 * jc], b1 = (__bf16)Ts[kr][2 * jc + 1];
        unsigned u = (unsigned)__builtin_bit_cast(unsigned short, b0)
                   | ((unsigned)__builtin_bit_cast(unsigned short, b1) << 16);
        W2[(size_t)(k0 + kr) * 256 + (j0 >> 1) + jc] = u;
    }
}

// W_ih[:, :256] permuted rows -> bf16 [2048][256] (gate-interleaved)
__global__ __launch_bounds__(256) void k_cvt_wih_r(const float* __restrict__ W_ih,
                                                   __bf16* __restrict__ o) {
    int n = blockIdx.x, k = threadIdx.x;
    int row = gperm(n);
    o[(size_t)n * 256 + k] = (__bf16)W_ih[(size_t)row * 768 + k];
}

// Wcat[n][k]: k<512 -> W_ih[pi(n)][256+k], else W_hh[pi(n)][k-512]   (bf16)
__global__ __launch_bounds__(256) void k_pack_wcat(const float* __restrict__ W_ih,
                                                   const float* __restrict__ W_hh,
                                                   __bf16* __restrict__ Wcat) {
    int n = blockIdx.x, t = threadIdx.x;
    int row = gperm(n);
#pragma unroll
    for (int i = 0; i < 4; ++i) {
        int k = t + i * 256;
        float v = (k < 512) ? W_ih[(size_t)row * 768 + 256 + k]
                            : W_hh[(size_t)row * 512 + (k - 512)];
        Wcat[(size_t)n * 1024 + k] = (__bf16)v;
    }
}

__global__ __launch_bounds__(256) void k_pack_biasr(const float* __restrict__ b_ih,
                                                    const float* __restrict__ b_hh,
                                                    float* __restrict__ bsum_r) {
    int n = blockIdx.x * 256 + threadIdx.x;
    int row = gperm(n);
    bsum_r[n] = b_ih[row] + b_hh[row];
}

__global__ __launch_bounds__(256) void k_embed(const int* __restrict__ dec,
                                               const float* __restrict__ emb,
                                               const float* __restrict__ pose,
                                               __bf16* __restrict__ out) {
    int bx = blockIdx.x;
    int s = bx >> 7, b = bx & 127;
    int e = threadIdx.x;
    int tok = dec[b * S_ + s];
    out[(size_t)bx * E_ + e] = (__bf16)(emb[tok * E_ + e] + pose[s * E_ + e]);
}

// mean_enc -> h0 (bf16 into Abuf0 h-part), c0 (f32 cbuf). Coalesced GEMV (wave-per-j).
__global__ __launch_bounds__(1024) void k_init2(const float* __restrict__ enc,
                                                const float* __restrict__ ihw, const float* __restrict__ ihb,
                                                const float* __restrict__ icw, const float* __restrict__ icb,
                                                __bf16* __restrict__ Abuf0, float* __restrict__ cbuf) {
    __shared__ float pm[1024];
    __shared__ __align__(16) float mean[512];
    int b = blockIdx.x, t = threadIdx.x;
    int d = t & 511, q = t >> 9;
    const float* ep = enc + ((size_t)b * 196 + q * 98) * 512 + d;
    float sum = 0.f;
#pragma unroll 7
    for (int n = 0; n < 98; ++n) sum += ep[(size_t)n * 512];
    pm[t] = sum;
    __syncthreads();
    if (t < 512) mean[t] = (pm[t] + pm[t + 512]) * (1.f / 196.f);
    __syncthreads();
    int w = t >> 6, ln = t & 63;
    float4 m4a = *(const float4*)&mean[ln * 8];
    float4 m4b = *(const float4*)&mean[ln * 8 + 4];
#pragma unroll 4
    for (int i = 0; i < 32; ++i) {
        int j = i * 16 + w;
        const float4* wh = (const float4*)&ihw[(size_t)j * 512 + ln * 8];
        const float4* wc = (const float4*)&icw[(size_t)j * 512 + ln * 8];
        float4 ha = wh[0], hb = wh[1], ca = wc[0], cb = wc[1];
        float ah = m4a.x * ha.x + m4a.y * ha.y + m4a.z * ha.z + m4a.w * ha.w
                 + m4b.x * hb.x + m4b.y * hb.y + m4b.z * hb.z + m4b.w * hb.w;
        float ac = m4a.x * ca.x + m4a.y * ca.y + m4a.z * ca.z + m4a.w * ca.w
                 + m4b.x * cb.x + m4b.y * cb.y + m4b.z * cb.z + m4b.w * cb.w;
#pragma unroll
        for (int off = 32; off; off >>= 1) {
            ah += __shfl_xor(ah, off);
            ac += __shfl_xor(ac, off);
        }
        if (ln == 0) {
            Abuf0[(size_t)b * 1024 + 512 + j] = (__bf16)(ah + ihb[j]);
            cbuf[b * 512 + j] = ac + icb[j];
        }
    }
}

// ---------------- bf16 MFMA GEMM (proven core, + lda param) ----------------
// MODE 0: f32 out, remap row (s*128+b -> b*25+s), guard n<Nreal, +bias, XCD-swizzled grid (fcn)
// MODE 1: bf16 out, +bias (u_hs, gatespre)
template<int MODE>
__global__ __launch_bounds__(256) void k_mfma_gemm(
    const __bf16* __restrict__ A, int lda, const __bf16* __restrict__ Bm,
    const float* __restrict__ bias1, void* __restrict__ Cout,
    int K, int Nreal, int ldc) {
    __shared__ __align__(16) __bf16 As[128 * 64];
    __shared__ __align__(16) __bf16 Bs[128 * 64];
    int tid = threadIdx.x;
    int lane = tid & 63, w = tid >> 6;
    int m0, n0;
    if (MODE == 0) {
        // bijective XCD swizzle (m204): consecutive wgids (same fcw panel) -> same XCD
        int nwg = gridDim.x * gridDim.y;
        int bid = blockIdx.y * gridDim.x + blockIdx.x;
        int q = nwg >> 3, r = nwg & 7;
        int xcd = bid & 7, lid = bid >> 3;
        int wgid = (xcd < r) ? xcd * (q + 1) + lid : r * (q + 1) + (xcd - r) * q + lid;
        m0 = (wgid % gridDim.x) * 128;
        n0 = (wgid / gridDim.x) * 128;
    } else {
        m0 = blockIdx.x * 128;
        n0 = blockIdx.y * 128;
    }
    int wm = (w & 1) * 64, wn = (w >> 1) * 64;
    f32x4 acc[4][4] = {};
    int srow = tid >> 3;
    int ke = (tid & 7) * 8;
    int kgw = tid & 7;

    for (int k0 = 0; k0 < K; k0 += 64) {
#pragma unroll
        for (int it = 0; it < 4; ++it) {
            int row = it * 32 + srow;
            bf16x8 av = *(const bf16x8*)(A + (size_t)(m0 + row) * lda + k0 + ke);
            bf16x8 bv = *(const bf16x8*)(Bm + (size_t)(n0 + row) * K + k0 + ke);
            int kg = kgw ^ (row & 7);
            *(bf16x8*)&As[row * 64 + kg * 8] = av;
            *(bf16x8*)&Bs[row * 64 + kg * 8] = bv;
        }
        __syncthreads();
        bf16x8 af[4][2], bfr[4][2];
#pragma unroll
        for (int f = 0; f < 4; ++f) {
#pragma unroll
            for (int ks = 0; ks < 2; ++ks) {
                int ra = wm + f * 16 + (lane & 15);
                int rb = wn + f * 16 + (lane & 15);
                int kgl = ks * 4 + (lane >> 4);
                af[f][ks]  = *(const bf16x8*)&As[ra * 64 + (kgl ^ (ra & 7)) * 8];
                bfr[f][ks] = *(const bf16x8*)&Bs[rb * 64 + (kgl ^ (rb & 7)) * 8];
            }
        }
#pragma unroll
        for (int fm = 0; fm < 4; ++fm)
#pragma unroll
            for (int fn = 0; fn < 4; ++fn)
#pragma unroll
                for (int ks = 0; ks < 2; ++ks)
                    acc[fm][fn] = __builtin_amdgcn_mfma_f32_16x16x32_bf16(
                        af[fm][ks], bfr[fn][ks], acc[fm][fn], 0, 0, 0);
        __syncthreads();
    }
    int cm = (lane >> 4) * 4, cn = lane & 15;
#pragma unroll
    for (int fm = 0; fm < 4; ++fm) {
#pragma unroll
        for (int fn = 0; fn < 4; ++fn) {
#pragma unroll
            for (int r = 0; r < 4; ++r) {
                int gm = m0 + wm + fm * 16 + cm + r;
                int gn = n0 + wn + fn * 16 + cn;
                float v = acc[fm][fn][r];
                if (MODE == 0) {
                    if (gn < Nreal) {
                        int orow = (gm & 127) * S_ + (gm >> 7);
                        ((float*)Cout)[(size_t)orow * ldc + gn] = v + bias1[gn];
                    }
                } else {
                    ((__bf16*)Cout)[(size_t)gm * ldc + gn] = (__bf16)(v + bias1[gn]);
                }
            }
        }
    }
}

// ---------------- K1: per-step attention, 1024 thr, max-free wave-redundant softmax ----------------
__global__ __launch_bounds__(1024) void k_attn2(
    const __bf16* __restrict__ u_hs,      // [25088][512] bf16
    const unsigned* __restrict__ enc2,    // enc bf16 pairs [25088][256]
    const unsigned* __restrict__ W2,      // [512][256] packed Ww^T
    const float* __restrict__ Wb, const float* __restrict__ Aw,
    __bf16* __restrict__ Abuf,            // [128][1024]: read h (512..1023), write ctx (0..511)
    float* __restrict__ alphas, int s) {
    __shared__ __align__(16) float hs[512];
    __shared__ float wah[512];
    __shared__ float pc[2048];
    __shared__ float sc[200];             // holds E = exp(score)
    int b = blockIdx.x, t = threadIdx.x;
    int ln = t & 63, w = t >> 6;

    // h (bf16) -> LDS f32
    if (t < 256) {
        unsigned u = ((const unsigned*)Abuf)[b * 512 + 256 + t];
        hs[2 * t] = bflo(u); hs[2 * t + 1] = bfhi(u);
    }
    __syncthreads();
    // w_ah = h @ Ww^T + Wb  (coalesced packed W2, 4-way k-split — R5/R8-proven)
    {
        int jp = t & 255, kq = t >> 8;
        float a0 = 0.f, a1 = 0.f;
        const unsigned* wp = W2 + (size_t)(kq * 128) * 256 + jp;
        const float4* h4 = (const float4*)(hs + kq * 128);
#pragma unroll 4
        for (int k4 = 0; k4 < 32; ++k4) {
            float4 hk = h4[k4];
            unsigned w0 = wp[(k4 * 4 + 0) * 256];
            unsigned w1 = wp[(k4 * 4 + 1) * 256];
            unsigned w2 = wp[(k4 * 4 + 2) * 256];
            unsigned w3 = wp[(k4 * 4 + 3) * 256];
            a0 += hk.x * bflo(w0); a1 += hk.x * bfhi(w0);
            a0 += hk.y * bflo(w1); a1 += hk.y * bfhi(w1);
            a0 += hk.z * bflo(w2); a1 += hk.z * bfhi(w2);
            a0 += hk.w * bflo(w3); a1 += hk.w * bfhi(w3);
        }
        pc[kq * 512 + 2 * jp] = a0;
        pc[kq * 512 + 2 * jp + 1] = a1;
    }
    __syncthreads();
    if (t < 512)
        wah[t] = pc[t] + pc[512 + t] + pc[1024 + t] + pc[1536 + t] + Wb[t];
    __syncthreads();
    // scores -> E = exp(score): 196 rows over 16 waves (max-free: |score| small, Ab cancels)
    {
        float av[8], wv[8];
#pragma unroll
        for (int i = 0; i < 8; ++i) { av[i] = Aw[ln * 8 + i]; wv[i] = wah[ln * 8 + i]; }
        for (int n = w; n < NF_; n += 16) {
            bf16x8 u8 = *(const bf16x8*)(u_hs + ((size_t)(b * NF_ + n)) * 512 + ln * 8);
            float acc = 0.f;
#pragma unroll
            for (int i = 0; i < 8; ++i)
                acc += fast_tanhf((float)u8[i] + wv[i]) * av[i];
#pragma unroll
            for (int off = 32; off; off >>= 1) acc += __shfl_xor(acc, off);
            if (ln == 0) sc[n] = __expf(acc);
        }
    }
    __syncthreads();
    // wave-redundant normalizer. 196 = 3*64 + 4: lane ln sums sc[ln], sc[ln+64],
    // sc[ln+128], and (ln<4) sc[ln+192].  [R10 BUG FIX: (ln<68)?sc[ln+128] missed 192..195]
    float sum = sc[ln] + sc[ln + 64] + sc[ln + 128];
    if (ln < 4) sum += sc[ln + 192];
#pragma unroll
    for (int off = 32; off; off >>= 1) sum += __shfl_xor(sum, off);
    float inv = __fdividef(1.f, sum);
    if (t < NF_) alphas[((size_t)b * S_ + s) * NF_ + t] = sc[t] * inv;
    // context = (E @ enc) * inv (4-way row split)
    {
        int p2 = t & 255, q2 = t >> 8;
        float c0 = 0.f, c1 = 0.f;
        for (int i = q2; i < NF_; i += 4) {
            unsigned u = enc2[((size_t)(b * NF_ + i)) * 256 + p2];
            float a = sc[i];
            c0 += a * bflo(u); c1 += a * bfhi(u);
        }
        pc[q2 * 512 + 2 * p2] = c0;
        pc[q2 * 512 + 2 * p2 + 1] = c1;
    }
    __syncthreads();
    if (t < 512)
        Abuf[(size_t)b * 1024 + t] =
            (__bf16)((pc[t] + pc[512 + t] + pc[1024 + t] + pc[1536 + t]) * inv);
}

// ---------------- K2: gates MFMA GEMM, 32x64 tiles + 2-way K-split (R8-proven) ----------------
__global__ __launch_bounds__(256) void k_gates(
    const __bf16* __restrict__ Abuf,      // [128][1024] = [ctx(s) | h(s)]
    const __bf16* __restrict__ Wcat,      // [2048][1024]
    const __bf16* __restrict__ gatespre,  // [3200][2048] bf16, gate-interleaved cols
    float* __restrict__ cbuf,             // [128][512] f32
    __bf16* __restrict__ AbufN,           // [128][1024]: write h(s+1) into cols 512..1023
    __bf16* __restrict__ Hall_bf,         // [26][128][512]
    int s) {
    __shared__ __align__(16) __bf16 As[2][32 * 64];
    __shared__ __align__(16) __bf16 Bs[2][64 * 64];
    __shared__ float Red[2048];
    int tid = threadIdx.x;
    int lane = tid & 63, w = tid >> 6;
    int m0 = blockIdx.x * 32, n0 = blockIdx.y * 64;
    int kh = w >> 1, wm = (w & 1) * 16;
    f32x4 acc[4] = {};
    int srow = tid >> 3;          // 0..31
    int ke = (tid & 7) * 8;
    int kgw = tid & 7;

    for (int k0 = 0; k0 < 512; k0 += 64) {
#pragma unroll
        for (int h = 0; h < 2; ++h) {
            int kb = h * 512 + k0;
            bf16x8 av = *(const bf16x8*)(Abuf + (size_t)(m0 + srow) * 1024 + kb + ke);
            int kg = kgw ^ (srow & 7);
            *(bf16x8*)&As[h][srow * 64 + kg * 8] = av;
#pragma unroll
            for (int it = 0; it < 2; ++it) {
                int row = it * 32 + srow;
                bf16x8 bv = *(const bf16x8*)(Wcat + (size_t)(n0 + row) * 1024 + kb + ke);
                int kg2 = kgw ^ (row & 7);
                *(bf16x8*)&Bs[h][row * 64 + kg2 * 8] = bv;
            }
        }
        __syncthreads();
        bf16x8 af[2], bfr[4][2];
#pragma unroll
        for (int ks = 0; ks < 2; ++ks) {
            int ra = wm + (lane & 15);
            int kgl = ks * 4 + (lane >> 4);
            af[ks] = *(const bf16x8*)&As[kh][ra * 64 + ((kgl ^ (ra & 7))) * 8];
#pragma unroll
            for (int fn = 0; fn < 4; ++fn) {
                int rb = fn * 16 + (lane & 15);
                bfr[fn][ks] = *(const bf16x8*)&Bs[kh][rb * 64 + ((kgl ^ (rb & 7))) * 8];
            }
        }
#pragma unroll
        for (int fn = 0; fn < 4; ++fn)
#pragma unroll
            for (int ks = 0; ks < 2; ++ks)
                acc[fn] = __builtin_amdgcn_mfma_f32_16x16x32_bf16(
                    af[ks], bfr[fn][ks], acc[fn], 0, 0, 0);
        __syncthreads();
    }
    // reduce the kh=1 half into kh=0 waves
    int base = ((w & 1) * 64 + lane) * 16;
    if (kh == 1) {
#pragma unroll
        for (int fn = 0; fn < 4; ++fn)
#pragma unroll
            for (int r = 0; r < 4; ++r) Red[base + fn * 4 + r] = acc[fn][r];
    }
    __syncthreads();
    if (kh == 0) {
#pragma unroll
        for (int fn = 0; fn < 4; ++fn)
#pragma unroll
            for (int r = 0; r < 4; ++r) acc[fn][r] += Red[base + fn * 4 + r];
        // epilogue: lane owns unit j for all 4 gates (fn = gate)
        int cm = (lane >> 4) * 4, cn = lane & 15;
        int j = (n0 >> 6) * 16 + cn;
#pragma unroll
        for (int r = 0; r < 4; ++r) {
            int b = m0 + wm + cm + r;
            const __bf16* gp = gatespre + ((size_t)(s * B_ + b)) * G4_ + n0 + cn;
            float qi = acc[0][r] + (float)gp[0];
            float qf = acc[1][r] + (float)gp[16];
            float qg = acc[2][r] + (float)gp[32];
            float qo = acc[3][r] + (float)gp[48];
            float ig = fast_sigf(qi), fg = fast_sigf(qf);
            float gg = fast_tanhf(qg), og = fast_sigf(qo);
            int ci = b * 512 + j;
            float cnew = fg * cbuf[ci] + ig * gg;
            float hn = og * fast_tanhf(cnew);
            cbuf[ci] = cnew;
            __bf16 hb = (__bf16)hn;
            AbufN[(size_t)b * 1024 + 512 + j] = hb;
            Hall_bf[(size_t)(s + 1) * 65536 + ci] = hb;
        }
    }
}

extern "C" void kernel_launch(void* const* d_in, const int* in_sizes, int n_in,
                              void* d_out, int out_size, void* d_ws, size_t ws_size,
                              hipStream_t stream) {
    const int*   dec  = (const int*)d_in[0];
    const float* enc  = (const float*)d_in[1];
    const float* emb  = (const float*)d_in[2];
    const float* pose = (const float*)d_in[3];
    const float* Uw   = (const float*)d_in[4];
    const float* Ub   = (const float*)d_in[5];
    const float* Ww   = (const float*)d_in[6];
    const float* Wb   = (const float*)d_in[7];
    const float* Aw   = (const float*)d_in[8];
    // d_in[9] = Ab: cancels in softmax
    const float* ihw  = (const float*)d_in[10];
    const float* ihb  = (const float*)d_in[11];
    const float* icw  = (const float*)d_in[12];
    const float* icb  = (const float*)d_in[13];
    const float* W_ih = (const float*)d_in[14];
    const float* W_hh = (const float*)d_in[15];
    const float* b_ih = (const float*)d_in[16];
    const float* b_hh = (const float*)d_in[17];
    const float* fcw  = (const float*)d_in[18];
    const float* fcb  = (const float*)d_in[19];
    float* out = (float*)d_out;
    char*  wsb = (char*)d_ws;

    // ---- workspace layout (bytes), ~87 MB ----
    size_t o = 0;
    __bf16*   enc_bf   = (__bf16*)(wsb + o); o += (size_t)25088 * 512 * 2;   // 25,690,112
    __bf16*   u_hs_bf  = (__bf16*)(wsb + o); o += (size_t)25088 * 512 * 2;   // 25,690,112
    __bf16*   gpre_bf  = (__bf16*)(wsb + o); o += (size_t)3200 * 2048 * 2;   // 13,107,200
    __bf16*   Hall_bf  = (__bf16*)(wsb + o); o += (size_t)26 * 65536 * 2;    //  3,407,872
    float*    cbuf     = (float*)(wsb + o);  o += (size_t)65536 * 4;         //    262,144
    __bf16*   Abuf     = (__bf16*)(wsb + o); o += (size_t)2 * 128 * 1024 * 2;//    524,288
    __bf16*   Uw_bf    = (__bf16*)(wsb + o); o += (size_t)262144 * 2;        //    524,288
    unsigned* W2       = (unsigned*)(wsb + o); o += (size_t)512 * 256 * 4;   //    524,288
    __bf16*   WihE_r   = (__bf16*)(wsb + o); o += (size_t)2048 * 256 * 2;    //  1,048,576
    __bf16*   embeds_bf= (__bf16*)(wsb + o); o += (size_t)3200 * 256 * 2;    //  1,638,400
    __bf16*   Wcat     = (__bf16*)(wsb + o); o += (size_t)2048 * 1024 * 2;   //  4,194,304
    float*    bsum_r   = (float*)(wsb + o);  o += (size_t)2048 * 4;          //      8,192
    __bf16*   fcw_bf   = (__bf16*)(wsb + o); o += (size_t)VPAD_ * 512 * 2;   // 10,354,688

    // ---- setup (independent) ----
    k_cvt<<<12544, 256, 0, stream>>>(enc, enc_bf, 3211264);
    k_cvt<<<256, 256, 0, stream>>>(Uw, Uw_bf, 65536);
    k_pack_ww<<<dim3(16, 8), 256, 0, stream>>>(Ww, W2);
    k_cvt_wih_r<<<2048, 256, 0, stream>>>(W_ih, WihE_r);
    k_pack_wcat<<<2048, 256, 0, stream>>>(W_ih, W_hh, Wcat);
    k_pack_biasr<<<8, 256, 0, stream>>>(b_ih, b_hh, bsum_r);
    k_embed<<<S_ * B_, 256, 0, stream>>>(dec, emb, pose, embeds_bf);
    k_init2<<<B_, 1024, 0, stream>>>(enc, ihw, ihb, icw, icb, Abuf, cbuf);
    k_cvt_fcw<<<5056, 256, 0, stream>>>(fcw, fcw_bf);

    // u_hs = enc @ Uw^T + Ub -> bf16 [25088,512]
    k_mfma_gemm<1><<<dim3(196, 4), 256, 0, stream>>>(enc_bf, 512, Uw_bf, Ub,
                                                     u_hs_bf, 512, 512, 512);
    // gates_pre = embeds @ WihE_r^T + bsum_r -> bf16 [3200,2048] (gate-interleaved cols)
    k_mfma_gemm<1><<<dim3(25, 16), 256, 0, stream>>>(embeds_bf, 256, WihE_r, bsum_r,
                                                     gpre_bf, 256, 2048, 2048);

    // ---- 25 steps x 2 kernels ----
    for (int s = 0; s < S_; ++s) {
        __bf16* Ap = Abuf + (size_t)(s & 1) * 131072;
        __bf16* An = Abuf + (size_t)((s + 1) & 1) * 131072;
        k_attn2<<<B_, 1024, 0, stream>>>(u_hs_bf, (const unsigned*)enc_bf, W2, Wb, Aw,
                                         Ap, out + 32000000, s);
        k_gates<<<dim3(4, 32), 256, 0, stream>>>(Ap, Wcat, gpre_bf, cbuf, An, Hall_bf, s);
    }

    // outs = Hall_bf[1..25] @ fcn_w^T + fcn_b -> f32 [B,S,V]  (XCD-swizzled grid)
    k_mfma_gemm<0><<<dim3(25, 79), 256, 0, stream>>>(Hall_bf + 65536, 512, fcw_bf, fcb,
                                                     out, 512, V_, V_);
}